// Round 4
// baseline (390.523 us; speedup 1.0000x reference)
//
#include <hip/hip_runtime.h>
#include <stdint.h>

#define NDIM 256
#define BATCH 65536
#define NROT 32640          // 256*255/2
#define PBLK 16             // parallel Givens blocks per matrix

typedef float  f32x4 __attribute__((ext_vector_type(4)));
typedef short  s16x8 __attribute__((ext_vector_type(8)));
typedef unsigned int u32x4 __attribute__((ext_vector_type(4)));
typedef unsigned int u32x2 __attribute__((ext_vector_type(2)));

// round-to-nearest-even float -> bf16 bits
static __device__ __forceinline__ unsigned short f2bf(float f) {
    unsigned int u = __float_as_uint(f);
    u += 0x7fffu + ((u >> 16) & 1u);
    return (unsigned short)(u >> 16);
}

// ---------------- workspace layout (bytes) ----------------
static constexpr size_t OFF_CS   = 0;
static constexpr size_t OFF_PING = 524288;
static constexpr size_t OFF_PONG = OFF_PING + 8388608;
static constexpr size_t OFF_ABT  = OFF_PONG + 8388608;
static constexpr size_t OFF_INV  = OFF_ABT + 262144;
static constexpr size_t OFF_XBF  = OFF_INV + 262144;                 // 32 MB bf16 x
static constexpr size_t WS_BIG   = OFF_XBF + (size_t)BATCH * 256 * 2;

// ---------------- kernel 1: cos/sin of all rotation angles ----------------
__global__ void k_cossin(const float* __restrict__ r1, const float* __restrict__ r2,
                         float2* __restrict__ cs) {
    int i = blockIdx.x * 256 + threadIdx.x;
    if (i < 2 * NROT) {
        float th = (i < NROT) ? r1[i] : r2[i - NROT];
        cs[i] = make_float2(cosf(th), sinf(th));
    }
}

// ---------------- kernel 2: build PBLK partial Givens products per matrix ----
// Wavefront-skewed: 4 consecutive sweeps fused. The 4 active rows live in
// registers u[0..3]; per steady j-step we do 1 LDS read + 4 rotations +
// 1 LDS write. Angles come from global cs via forced-scalar (SMEM) loads.
// Row reads use an explicit 8-deep register prefetch pipeline.
// Legality: rot(m0+a, j) commutes with rot(m0, j') for j' > j (disjoint rows),
// so the skewed interleave preserves the exact product order.
__global__ __launch_bounds__(64) void k_blocks(const float2* __restrict__ cs,
                                               float* __restrict__ bmats) {
    __shared__ float colb[256 * 64];
    const int t = threadIdx.x;          // column within chunk
    const int chunk = blockIdx.x;       // 0..3 (64 cols each)
    const int b = blockIdx.y;           // block 0..PBLK-1
    const int set = blockIdx.z;         // 0 = rots1, 1 = rots2
    const int col0 = chunk * 64;

    // 4-aligned sweep partition: s0/s1 = first multiple-of-4 sweep whose
    // rotation-prefix count reaches tlo/thi.
    const int tlo = b * (NROT / PBLK);
    const int thi = (b + 1) * (NROT / PBLK);
    int s0 = -1, s1 = -1;
    for (int i = 0; i <= 256; i += 4) {
        int basei = i * 255 - (i * (i - 1)) / 2;   // rotations before sweep i
        if (s0 < 0 && basei >= tlo) s0 = i;
        if (s1 < 0 && basei >= thi) s1 = i;
    }

    // init identity (this WG's 64 columns)
    {
        const f32x4 z = {0.f, 0.f, 0.f, 0.f};
        #pragma unroll 8
        for (int q = 0; q < 64; q++)
            *(f32x4*)&colb[(q * 64 + t) * 4] = z;
        colb[(col0 + t) * 64 + t] = 1.0f;
    }
    __syncthreads();

    const int csoff = set * NROT;
    for (int g = (s0 >> 2); g < (s1 >> 2); g++) {
        const int m0 = g * 4;
        int off[4];
        #pragma unroll
        for (int a = 0; a < 4; a++) {
            int m = m0 + a;
            int base = m * 255 - (m * (m - 1)) / 2;
            off[a] = csoff + base - m - 1;          // angle idx for (m,j) = off[a]+j
        }
        // active rows -> registers
        float u[4];
        #pragma unroll
        for (int a = 0; a < 4; a++) u[a] = colb[(m0 + a) * 64 + t];

        // triangle peel (sweep-major order): (m0,m0+1..3),(m0+1,m0+2..3),(m0+2,m0+3)
        #pragma unroll
        for (int a = 0; a < 3; a++) {
            #pragma unroll
            for (int bb = a + 1; bb < 4; bb++) {
                float2 cv = cs[__builtin_amdgcn_readfirstlane(off[a] + m0 + bb)];
                float nr = cv.y * u[a] + cv.x * u[bb];
                u[a] = cv.x * u[a] - cv.y * u[bb];
                u[bb] = nr;
            }
        }

        // steady state: j = m0+4 .. 255, 4 rotations per step
        const int jbeg = m0 + 4;
        float rjbuf[8];
        #pragma unroll
        for (int p = 0; p < 8; p++) {
            int jj = jbeg + p; jj = (jj < 255) ? jj : 255;   // clamped (guarded later)
            rjbuf[p] = colb[jj * 64 + t];
        }
        int j = jbeg;
        for (; j + 16 <= 256; j += 8) {
            #pragma unroll
            for (int p = 0; p < 8; p++) {
                float r = rjbuf[p];
                rjbuf[p] = colb[(j + p + 8) * 64 + t];       // prefetch depth 8
                #pragma unroll
                for (int a = 0; a < 4; a++) {
                    float2 cv = cs[__builtin_amdgcn_readfirstlane(off[a] + j + p)];
                    float nr = cv.y * u[a] + cv.x * r;
                    u[a] = cv.x * u[a] - cv.y * r;
                    r = nr;
                }
                colb[(j + p) * 64 + t] = r;
            }
        }
        // drain buffered rows (uniform guards, compile-time indices)
        #pragma unroll
        for (int p = 0; p < 8; p++) {
            if (j + p < 256) {
                float r = rjbuf[p];
                #pragma unroll
                for (int a = 0; a < 4; a++) {
                    float2 cv = cs[__builtin_amdgcn_readfirstlane(off[a] + j + p)];
                    float nr = cv.y * u[a] + cv.x * r;
                    u[a] = cv.x * u[a] - cv.y * r;
                    r = nr;
                }
                colb[(j + p) * 64 + t] = r;
            }
        }
        j += 8;
        for (; j < 256; j++) {
            float r = colb[j * 64 + t];
            #pragma unroll
            for (int a = 0; a < 4; a++) {
                float2 cv = cs[__builtin_amdgcn_readfirstlane(off[a] + j)];
                float nr = cv.y * u[a] + cv.x * r;
                u[a] = cv.x * u[a] - cv.y * r;
                r = nr;
            }
            colb[j * 64 + t] = r;
        }
        // store active rows back
        #pragma unroll
        for (int a = 0; a < 4; a++) colb[(m0 + a) * 64 + t] = u[a];
    }

    float* outm = bmats + (size_t)(set * PBLK + b) * 65536;
    for (int r = 0; r < 256; r++)
        outm[(size_t)r * 256 + col0 + t] = colb[r * 64 + t];
}

// ---------------- kernel 3: pairwise combine round (fp32 256^3 matmul) ------
__global__ __launch_bounds__(256) void k_combine(const float* __restrict__ src,
                                                 float* __restrict__ dst, int half) {
    const int by = blockIdx.y;
    const int set = by / half, pidx = by % half;
    const float* Am = src + (size_t)(set * 2 * half + 2 * pidx + 1) * 65536;
    const float* Bm = src + (size_t)(set * 2 * half + 2 * pidx) * 65536;
    float* Dm = dst + (size_t)(set * half + pidx) * 65536;
    const int tr = blockIdx.x >> 2, tc = blockIdx.x & 3;

    __shared__ float As[64 * 32];
    __shared__ float Bs[32 * 64];
    const int tid = threadIdx.x;
    const int tx = tid & 15, ty = tid >> 4;

    float acc[4][4] = {};
    for (int kb = 0; kb < 8; kb++) {
        __syncthreads();
        #pragma unroll
        for (int it = 0; it < 2; it++) {
            int flat = tid + it * 256;
            int r = flat >> 3, c4 = flat & 7;
            f32x4 v = *(const f32x4*)&Am[(size_t)(tr * 64 + r) * 256 + kb * 32 + c4 * 4];
            *(f32x4*)&As[r * 32 + c4 * 4] = v;
        }
        #pragma unroll
        for (int it = 0; it < 2; it++) {
            int flat = tid + it * 256;
            int r = flat >> 4, c4 = flat & 15;
            f32x4 v = *(const f32x4*)&Bm[(size_t)(kb * 32 + r) * 256 + tc * 64 + c4 * 4];
            *(f32x4*)&Bs[r * 64 + c4 * 4] = v;
        }
        __syncthreads();
        #pragma unroll 8
        for (int kk = 0; kk < 32; kk++) {
            f32x4 bv = *(const f32x4*)&Bs[kk * 64 + tx * 4];
            float a0 = As[(ty * 4 + 0) * 32 + kk];
            float a1 = As[(ty * 4 + 1) * 32 + kk];
            float a2 = As[(ty * 4 + 2) * 32 + kk];
            float a3 = As[(ty * 4 + 3) * 32 + kk];
            #pragma unroll
            for (int j = 0; j < 4; j++) {
                acc[0][j] += a0 * bv[j];
                acc[1][j] += a1 * bv[j];
                acc[2][j] += a2 * bv[j];
                acc[3][j] += a3 * bv[j];
            }
        }
    }
    #pragma unroll
    for (int i = 0; i < 4; i++) {
        f32x4 v = { acc[i][0], acc[i][1], acc[i][2], acc[i][3] };
        *(f32x4*)&Dm[(size_t)(tr * 64 + ty * 4 + i) * 256 + tc * 64 + tx * 4] = v;
    }
}

// ---------------- kernel 4: AT/BT = M2 @ diag(cos|sin(phases)) @ M1 -> bf16 -
__global__ __launch_bounds__(256) void k_abt(const float* __restrict__ mats,
                                             const float* __restrict__ phases,
                                             unsigned short* __restrict__ abt) {
    const float* Am = mats + 65536;    // M2
    const float* Bm = mats;            // M1
    const int v = blockIdx.y;          // 0: cos (AT), 1: sin (BT)
    const int tr = blockIdx.x >> 2, tc = blockIdx.x & 3;

    __shared__ float As[64 * 32];
    __shared__ float Bs[32 * 64];
    const int tid = threadIdx.x;
    const int tx = tid & 15, ty = tid >> 4;

    float acc[4][4] = {};
    for (int kb = 0; kb < 8; kb++) {
        __syncthreads();
        #pragma unroll
        for (int it = 0; it < 2; it++) {
            int flat = tid + it * 256;
            int r = flat >> 3, c4 = flat & 7;
            f32x4 vv = *(const f32x4*)&Am[(size_t)(tr * 64 + r) * 256 + kb * 32 + c4 * 4];
            *(f32x4*)&As[r * 32 + c4 * 4] = vv;
        }
        #pragma unroll
        for (int it = 0; it < 2; it++) {
            int flat = tid + it * 256;
            int r = flat >> 4, c4 = flat & 15;
            int kg = kb * 32 + r;
            float ph = phases[kg];
            float sc = v ? sinf(ph) : cosf(ph);
            f32x4 vv = *(const f32x4*)&Bm[(size_t)kg * 256 + tc * 64 + c4 * 4];
            vv[0] *= sc; vv[1] *= sc; vv[2] *= sc; vv[3] *= sc;
            *(f32x4*)&Bs[r * 64 + c4 * 4] = vv;
        }
        __syncthreads();
        #pragma unroll 8
        for (int kk = 0; kk < 32; kk++) {
            f32x4 bv = *(const f32x4*)&Bs[kk * 64 + tx * 4];
            float a0 = As[(ty * 4 + 0) * 32 + kk];
            float a1 = As[(ty * 4 + 1) * 32 + kk];
            float a2 = As[(ty * 4 + 2) * 32 + kk];
            float a3 = As[(ty * 4 + 3) * 32 + kk];
            #pragma unroll
            for (int j = 0; j < 4; j++) {
                acc[0][j] += a0 * bv[j];
                acc[1][j] += a1 * bv[j];
                acc[2][j] += a2 * bv[j];
                acc[3][j] += a3 * bv[j];
            }
        }
    }
    #pragma unroll
    for (int i = 0; i < 4; i++) {
        unsigned short h0 = f2bf(acc[i][0]), h1 = f2bf(acc[i][1]);
        unsigned short h2 = f2bf(acc[i][2]), h3 = f2bf(acc[i][3]);
        u32x2 pk = { (unsigned)h0 | ((unsigned)h1 << 16),
                     (unsigned)h2 | ((unsigned)h3 << 16) };
        *(u32x2*)&abt[(size_t)(v * 256 + tr * 64 + ty * 4 + i) * 256 + tc * 64 + tx * 4] = pk;
    }
}

// ---------------- kernel 5a: normalize rows -> bf16 (fast path) -------------
__global__ __launch_bounds__(256) void k_xnorm(const float* __restrict__ x,
                                               unsigned short* __restrict__ xbf) {
    const int row = blockIdx.x * 4 + (threadIdx.x >> 6);
    const int lane = threadIdx.x & 63;
    f32x4 v = *(const f32x4*)&x[(size_t)row * 256 + lane * 4];
    float s = v[0] * v[0] + v[1] * v[1] + v[2] * v[2] + v[3] * v[3];
    for (int off = 32; off; off >>= 1) s += __shfl_xor(s, off, 64);
    float sc = 1.0f / sqrtf(s);
    unsigned short h0 = f2bf(v[0] * sc), h1 = f2bf(v[1] * sc);
    unsigned short h2 = f2bf(v[2] * sc), h3 = f2bf(v[3] * sc);
    u32x2 pk = { (unsigned)h0 | ((unsigned)h1 << 16),
                 (unsigned)h2 | ((unsigned)h3 << 16) };
    *(u32x2*)&xbf[(size_t)row * 256 + lane * 4] = pk;
}

// ---------------- kernel 5b: per-row 1/||x|| (fallback path) ----------------
__global__ __launch_bounds__(256) void k_norm(const float* __restrict__ x,
                                              float* __restrict__ invn) {
    const int row = blockIdx.x * 4 + (threadIdx.x >> 6);
    const int lane = threadIdx.x & 63;
    f32x4 v = *(const f32x4*)&x[(size_t)row * 256 + lane * 4];
    float s = v[0] * v[0] + v[1] * v[1] + v[2] * v[2] + v[3] * v[3];
    for (int off = 32; off; off >>= 1) s += __shfl_xor(s, off, 64);
    if (lane == 0) invn[row] = 1.0f / sqrtf(s);
}

// ---------------- kernel 6a: GEMM + |.|^2 from pre-converted bf16 x ---------
// Grid (rb=512, cb=4): the 4 cb-blocks sharing an x-tile are 512 apart in
// linear WG id -> same XCD under round-robin dispatch -> x fetched once/XCD.
#define BKP 136   // padded LDS k-stride (bf16 elems)
__global__ __launch_bounds__(256) void k_gemm_bf(const unsigned short* __restrict__ xbf,
                                                 const unsigned short* __restrict__ abt,
                                                 float* __restrict__ out) {
    __shared__ unsigned short As[128 * BKP];
    __shared__ unsigned short Bs[128 * BKP];
    const int tid = threadIdx.x;
    const int rb = blockIdx.x;          // 0..511
    const int cb = blockIdx.y;          // 0..3  (64 out-cols each)
    const int lane = tid & 63, w = tid >> 6;

    f32x4 acc[16];
    #pragma unroll
    for (int i = 0; i < 16; i++) acc[i] = (f32x4){0.f, 0.f, 0.f, 0.f};

    for (int kb = 0; kb < 2; kb++) {
        __syncthreads();
        // stage x tile (128x128 bf16, 16B vector loads)
        #pragma unroll
        for (int it = 0; it < 8; it++) {
            int flat = tid + it * 256;            // 128 rows x 16 chunks(8 bf16)
            int r = flat >> 4, c8 = flat & 15;
            u32x4 vv = *(const u32x4*)&xbf[(size_t)(rb * 128 + r) * 256 + kb * 128 + c8 * 8];
            *(u32x4*)&As[r * BKP + c8 * 8] = vv;
        }
        // stage Bt tile: rows 0..63 from AT[cb*64..], rows 64..127 from BT[cb*64..]
        #pragma unroll
        for (int it = 0; it < 8; it++) {
            int flat = tid + it * 256;
            int r = flat >> 4, c8 = flat & 15;
            int gr = (r < 64) ? (cb * 64 + r) : (256 + cb * 64 + (r - 64));
            u32x4 vv = *(const u32x4*)&abt[(size_t)gr * 256 + kb * 128 + c8 * 8];
            *(u32x4*)&Bs[r * BKP + c8 * 8] = vv;
        }
        __syncthreads();
        #pragma unroll
        for (int ks = 0; ks < 4; ks++) {
            const int k0 = ks * 32 + (lane >> 4) * 8;
            s16x8 a[2], b[8];
            #pragma unroll
            for (int tm = 0; tm < 2; tm++)
                a[tm] = *(const s16x8*)&As[(w * 32 + tm * 16 + (lane & 15)) * BKP + k0];
            #pragma unroll
            for (int tn = 0; tn < 8; tn++)
                b[tn] = *(const s16x8*)&Bs[(tn * 16 + (lane & 15)) * BKP + k0];
            #pragma unroll
            for (int tm = 0; tm < 2; tm++)
                #pragma unroll
                for (int tn = 0; tn < 8; tn++)
                    acc[tm * 8 + tn] = __builtin_amdgcn_mfma_f32_16x16x32_bf16(
                        a[tm], b[tn], acc[tm * 8 + tn], 0, 0, 0);
        }
    }

    // epilogue: C/D layout col = lane&15, row = (lane>>4)*4 + reg
    const int qr = lane >> 4, c = lane & 15;
    #pragma unroll
    for (int tm = 0; tm < 2; tm++) {
        #pragma unroll
        for (int tn = 0; tn < 4; tn++) {
            f32x4 p = acc[tm * 8 + tn];
            f32x4 q = acc[tm * 8 + tn + 4];
            #pragma unroll
            for (int r = 0; r < 4; r++) {
                int m = w * 32 + tm * 16 + qr * 4 + r;
                out[(size_t)(rb * 128 + m) * 256 + cb * 64 + tn * 16 + c] =
                    p[r] * p[r] + q[r] * q[r];
            }
        }
    }
}

// ---------------- kernel 6b: GEMM + |.|^2 from fp32 x (fallback) ------------
__global__ __launch_bounds__(256) void k_gemm_f32(const float* __restrict__ x,
                                                  const unsigned short* __restrict__ abt,
                                                  const float* __restrict__ invn,
                                                  float* __restrict__ out) {
    __shared__ unsigned short As[128 * BKP];
    __shared__ unsigned short Bs[128 * BKP];
    const int tid = threadIdx.x;
    const int rb = blockIdx.x;
    const int cb = blockIdx.y;
    const int lane = tid & 63, w = tid >> 6;

    f32x4 acc[16];
    #pragma unroll
    for (int i = 0; i < 16; i++) acc[i] = (f32x4){0.f, 0.f, 0.f, 0.f};

    for (int kb = 0; kb < 2; kb++) {
        __syncthreads();
        #pragma unroll
        for (int it = 0; it < 16; it++) {
            int flat = tid + it * 256;
            int r = flat >> 5, c4 = flat & 31;
            f32x4 v = *(const f32x4*)&x[(size_t)(rb * 128 + r) * 256 + kb * 128 + c4 * 4];
            float sc = invn[rb * 128 + r];
            v[0] *= sc; v[1] *= sc; v[2] *= sc; v[3] *= sc;
            unsigned short h0 = f2bf(v[0]), h1 = f2bf(v[1]);
            unsigned short h2 = f2bf(v[2]), h3 = f2bf(v[3]);
            u32x2 pk = { (unsigned)h0 | ((unsigned)h1 << 16),
                         (unsigned)h2 | ((unsigned)h3 << 16) };
            *(u32x2*)&As[r * BKP + c4 * 4] = pk;
        }
        #pragma unroll
        for (int it = 0; it < 8; it++) {
            int flat = tid + it * 256;
            int r = flat >> 4, c8 = flat & 15;
            int gr = (r < 64) ? (cb * 64 + r) : (256 + cb * 64 + (r - 64));
            u32x4 vv = *(const u32x4*)&abt[(size_t)gr * 256 + kb * 128 + c8 * 8];
            *(u32x4*)&Bs[r * BKP + c8 * 8] = vv;
        }
        __syncthreads();
        #pragma unroll
        for (int ks = 0; ks < 4; ks++) {
            const int k0 = ks * 32 + (lane >> 4) * 8;
            s16x8 a[2], b[8];
            #pragma unroll
            for (int tm = 0; tm < 2; tm++)
                a[tm] = *(const s16x8*)&As[(w * 32 + tm * 16 + (lane & 15)) * BKP + k0];
            #pragma unroll
            for (int tn = 0; tn < 8; tn++)
                b[tn] = *(const s16x8*)&Bs[(tn * 16 + (lane & 15)) * BKP + k0];
            #pragma unroll
            for (int tm = 0; tm < 2; tm++)
                #pragma unroll
                for (int tn = 0; tn < 8; tn++)
                    acc[tm * 8 + tn] = __builtin_amdgcn_mfma_f32_16x16x32_bf16(
                        a[tm], b[tn], acc[tm * 8 + tn], 0, 0, 0);
        }
    }

    const int qr = lane >> 4, c = lane & 15;
    #pragma unroll
    for (int tm = 0; tm < 2; tm++) {
        #pragma unroll
        for (int tn = 0; tn < 4; tn++) {
            f32x4 p = acc[tm * 8 + tn];
            f32x4 q = acc[tm * 8 + tn + 4];
            #pragma unroll
            for (int r = 0; r < 4; r++) {
                int m = w * 32 + tm * 16 + qr * 4 + r;
                out[(size_t)(rb * 128 + m) * 256 + cb * 64 + tn * 16 + c] =
                    p[r] * p[r] + q[r] * q[r];
            }
        }
    }
}

// ---------------- host ------------------------------------------------------
extern "C" void kernel_launch(void* const* d_in, const int* in_sizes, int n_in,
                              void* d_out, int out_size, void* d_ws, size_t ws_size,
                              hipStream_t stream) {
    (void)in_sizes; (void)n_in; (void)out_size;
    const float* x      = (const float*)d_in[0];
    const float* rots1  = (const float*)d_in[1];
    const float* phases = (const float*)d_in[2];
    const float* rots2  = (const float*)d_in[3];
    float* out = (float*)d_out;
    char* ws = (char*)d_ws;

    float2*         cs    = (float2*)(ws + OFF_CS);
    float*          ping  = (float*)(ws + OFF_PING);
    float*          pong  = (float*)(ws + OFF_PONG);
    unsigned short* abt   = (unsigned short*)(ws + OFF_ABT);
    float*          invn  = (float*)(ws + OFF_INV);
    unsigned short* xbf   = (unsigned short*)(ws + OFF_XBF);

    k_cossin<<<(2 * NROT + 255) / 256, 256, 0, stream>>>(rots1, rots2, cs);
    k_blocks<<<dim3(4, PBLK, 2), 64, 0, stream>>>(cs, ping);
    k_combine<<<dim3(16, 16), 256, 0, stream>>>(ping, pong, 8);  // 16 -> 8 per set
    k_combine<<<dim3(16, 8),  256, 0, stream>>>(pong, ping, 4);  // 8 -> 4
    k_combine<<<dim3(16, 4),  256, 0, stream>>>(ping, pong, 2);  // 4 -> 2
    k_combine<<<dim3(16, 2),  256, 0, stream>>>(pong, ping, 1);  // 2 -> 1 (M1, M2)
    k_abt<<<dim3(16, 2), 256, 0, stream>>>(ping, phases, abt);

    if (ws_size >= WS_BIG) {
        k_xnorm<<<BATCH / 4, 256, 0, stream>>>(x, xbf);
        k_gemm_bf<<<dim3(BATCH / 128, 4), 256, 0, stream>>>(xbf, abt, out);
    } else {
        k_norm<<<BATCH / 4, 256, 0, stream>>>(x, invn);
        k_gemm_f32<<<dim3(BATCH / 128, 4), 256, 0, stream>>>(x, abt, invn, out);
    }
}

// Round 6
// 340.311 us; speedup vs baseline: 1.1475x; 1.1475x over previous
//
#include <hip/hip_runtime.h>
#include <stdint.h>

#define NDIM 256
#define BATCH 65536
#define NROT 32640          // 256*255/2

typedef float  f32x4 __attribute__((ext_vector_type(4)));
typedef short  s16x8 __attribute__((ext_vector_type(8)));
typedef unsigned int u32x4 __attribute__((ext_vector_type(4)));
typedef unsigned int u32x2 __attribute__((ext_vector_type(2)));

// round-to-nearest-even float -> bf16 bits
static __device__ __forceinline__ unsigned short f2bf(float f) {
    unsigned int u = __float_as_uint(f);
    u += 0x7fffu + ((u >> 16) & 1u);
    return (unsigned short)(u >> 16);
}

// ---------------- kernel 1: cos/sin of all rotation angles ----------------
__global__ void k_cossin(const float* __restrict__ r1, const float* __restrict__ r2,
                         float2* __restrict__ cs) {
    int i = blockIdx.x * 256 + threadIdx.x;
    if (i < 2 * NROT) {
        float th = (i < NROT) ? r1[i] : r2[i - NROT];
        cs[i] = make_float2(cosf(th), sinf(th));
    }
}

// ---------------- kernel 2: build pblk partial Givens products per matrix ---
// 4 sweeps fused (skewed schedule, order-equivalent: disjoint-row rotations
// commute). Active rows u0..u3 in registers. ALL angle reads come from LDS
// (csb staged per group; tri staged once) -- no SMEM/global in the hot loop
// (SMEM shares lgkmcnt with DS and drains the pipeline: R4 lesson).
// Identity padding ((c,s)=(1,0), colb rows 256..263) makes the steady loop
// guard-free with a fixed unroll-8 body -> compiler pipelines the DS reads.
__global__ __launch_bounds__(64) void k_blocks(const float2* __restrict__ cs,
                                               float* __restrict__ bmats, int pblk) {
    __shared__ float colb[264 * 64];
    __shared__ float2 csb[256 * 4];     // one group's steady angles, [jj][a]
    __shared__ float2 tri[20 * 6];      // all groups' triangle angles
    const int t = threadIdx.x;          // column within chunk
    const int chunk = blockIdx.x;       // 0..3 (64 cols each)
    const int b = blockIdx.y;           // 0..pblk-1
    const int set = blockIdx.z;         // 0 = rots1, 1 = rots2
    const int col0 = chunk * 64;
    const int csoff = set * NROT;

    // 4-aligned sweep partition
    const int target = NROT / pblk;
    const int tlo = b * target;
    const int thi = (b + 1) * target;
    int s0 = -1, s1 = -1;
    for (int i = 0; i <= 256; i += 4) {
        int pre = i * 255 - (i * (i - 1)) / 2;
        if (s0 < 0 && pre >= tlo) s0 = i;
        if (s1 < 0 && pre >= thi) s1 = i;
    }
    const int ngroups = (s1 - s0) >> 2;

    // zero colb (incl. pad rows), set identity diagonal
    {
        const f32x4 z = {0.f, 0.f, 0.f, 0.f};
        #pragma unroll 11
        for (int q = 0; q < 66; q++)
            *(f32x4*)&colb[(q * 64 + t) * 4] = z;
        colb[(col0 + t) * 64 + t] = 1.0f;
    }

    // stage all triangle angles (6 per group) into LDS
    // q -> pair (a,bb): 0->(0,1) 1->(0,2) 2->(0,3) 3->(1,2) 4->(1,3) 5->(2,3)
    for (int k = t; k < ngroups * 6; k += 64) {
        int g = k / 6, q = k - g * 6;
        int a  = (q < 3) ? 0 : ((q < 5) ? 1 : 2);
        int bb = (q < 3) ? (q + 1) : ((q < 5) ? (q - 1) : 3);   // R5 bug was q-2
        int m0 = s0 + g * 4;
        int m = m0 + a;
        int base = m * 255 - (m * (m - 1)) / 2;
        tri[k] = cs[csoff + base - m - 1 + (m0 + bb)];
    }
    // single-wave WG: DS pipe is in-order per wave, no barrier needed

    for (int g = 0; g < ngroups; g++) {
        const int m0 = s0 + g * 4;
        int off[4];
        #pragma unroll
        for (int a = 0; a < 4; a++) {
            int m = m0 + a;
            int base = m * 255 - (m * (m - 1)) / 2;
            off[a] = csoff + base - m - 1;          // angle for (m,j) = cs[off[a]+j]
        }
        const int n_j = 252 - m0;                   // #j in [m0+4, 256)
        const int n_p = (n_j > 0) ? ((n_j + 7) & ~7) : 0;

        // stage steady angles with identity padding: csb[jj*4 + a]
        for (int k = t; k < n_p * 4; k += 64) {
            int jj = k >> 2, a = k & 3;
            int j = m0 + 4 + jj;
            csb[k] = (j < 256) ? cs[off[a] + j] : make_float2(1.f, 0.f);
        }

        // active rows -> registers
        float u0 = colb[(m0 + 0) * 64 + t];
        float u1 = colb[(m0 + 1) * 64 + t];
        float u2 = colb[(m0 + 2) * 64 + t];
        float u3 = colb[(m0 + 3) * 64 + t];

        // triangle peel: (m0,m0+1..3), (m0+1,m0+2..3), (m0+2,m0+3)
        {
            float2 cv; float nr;
            cv = tri[g * 6 + 0]; nr = cv.y * u0 + cv.x * u1; u0 = cv.x * u0 - cv.y * u1; u1 = nr;
            cv = tri[g * 6 + 1]; nr = cv.y * u0 + cv.x * u2; u0 = cv.x * u0 - cv.y * u2; u2 = nr;
            cv = tri[g * 6 + 2]; nr = cv.y * u0 + cv.x * u3; u0 = cv.x * u0 - cv.y * u3; u3 = nr;
            cv = tri[g * 6 + 3]; nr = cv.y * u1 + cv.x * u2; u1 = cv.x * u1 - cv.y * u2; u2 = nr;
            cv = tri[g * 6 + 4]; nr = cv.y * u1 + cv.x * u3; u1 = cv.x * u1 - cv.y * u3; u3 = nr;
            cv = tri[g * 6 + 5]; nr = cv.y * u2 + cv.x * u3; u2 = cv.x * u2 - cv.y * u3; u3 = nr;
        }

        // steady state: guard-free, unroll 8, 8-deep row prefetch
        if (n_p > 0) {
            float rbuf[8];
            #pragma unroll
            for (int p = 0; p < 8; p++)
                rbuf[p] = colb[(m0 + 4 + p) * 64 + t];
            for (int c = 0; c < n_p; c += 8) {
                #pragma unroll
                for (int p = 0; p < 8; p++) {
                    const int j = m0 + 4 + c + p;
                    float r = rbuf[p];
                    int jn = j + 8; jn = (jn < 263) ? jn : 263;
                    rbuf[p] = colb[jn * 64 + t];
                    float2 a0 = csb[(c + p) * 4 + 0];
                    float2 a1 = csb[(c + p) * 4 + 1];
                    float2 a2 = csb[(c + p) * 4 + 2];
                    float2 a3 = csb[(c + p) * 4 + 3];
                    float nr;
                    nr = a0.y * u0 + a0.x * r; u0 = a0.x * u0 - a0.y * r; r = nr;
                    nr = a1.y * u1 + a1.x * r; u1 = a1.x * u1 - a1.y * r; r = nr;
                    nr = a2.y * u2 + a2.x * r; u2 = a2.x * u2 - a2.y * r; r = nr;
                    nr = a3.y * u3 + a3.x * r; u3 = a3.x * u3 - a3.y * r; r = nr;
                    colb[j * 64 + t] = r;
                }
            }
        }
        colb[(m0 + 0) * 64 + t] = u0;
        colb[(m0 + 1) * 64 + t] = u1;
        colb[(m0 + 2) * 64 + t] = u2;
        colb[(m0 + 3) * 64 + t] = u3;
    }

    float* outm = bmats + (size_t)(set * pblk + b) * 65536;
    for (int r = 0; r < 256; r++)
        outm[(size_t)r * 256 + col0 + t] = colb[r * 64 + t];
}

// ---------------- kernel 3: pairwise combine round (fp32 256^3 matmul) ------
__global__ __launch_bounds__(256) void k_combine(const float* __restrict__ src,
                                                 float* __restrict__ dst, int half) {
    const int by = blockIdx.y;
    const int set = by / half, pidx = by % half;
    const float* Am = src + (size_t)(set * 2 * half + 2 * pidx + 1) * 65536;
    const float* Bm = src + (size_t)(set * 2 * half + 2 * pidx) * 65536;
    float* Dm = dst + (size_t)(set * half + pidx) * 65536;
    const int tr = blockIdx.x >> 2, tc = blockIdx.x & 3;

    __shared__ float As[64 * 32];
    __shared__ float Bs[32 * 64];
    const int tid = threadIdx.x;
    const int tx = tid & 15, ty = tid >> 4;

    float acc[4][4] = {};
    for (int kb = 0; kb < 8; kb++) {
        __syncthreads();
        #pragma unroll
        for (int it = 0; it < 2; it++) {
            int flat = tid + it * 256;
            int r = flat >> 3, c4 = flat & 7;
            f32x4 v = *(const f32x4*)&Am[(size_t)(tr * 64 + r) * 256 + kb * 32 + c4 * 4];
            *(f32x4*)&As[r * 32 + c4 * 4] = v;
        }
        #pragma unroll
        for (int it = 0; it < 2; it++) {
            int flat = tid + it * 256;
            int r = flat >> 4, c4 = flat & 15;
            f32x4 v = *(const f32x4*)&Bm[(size_t)(kb * 32 + r) * 256 + tc * 64 + c4 * 4];
            *(f32x4*)&Bs[r * 64 + c4 * 4] = v;
        }
        __syncthreads();
        #pragma unroll 8
        for (int kk = 0; kk < 32; kk++) {
            f32x4 bv = *(const f32x4*)&Bs[kk * 64 + tx * 4];
            float a0 = As[(ty * 4 + 0) * 32 + kk];
            float a1 = As[(ty * 4 + 1) * 32 + kk];
            float a2 = As[(ty * 4 + 2) * 32 + kk];
            float a3 = As[(ty * 4 + 3) * 32 + kk];
            #pragma unroll
            for (int j = 0; j < 4; j++) {
                acc[0][j] += a0 * bv[j];
                acc[1][j] += a1 * bv[j];
                acc[2][j] += a2 * bv[j];
                acc[3][j] += a3 * bv[j];
            }
        }
    }
    #pragma unroll
    for (int i = 0; i < 4; i++) {
        f32x4 v = { acc[i][0], acc[i][1], acc[i][2], acc[i][3] };
        *(f32x4*)&Dm[(size_t)(tr * 64 + ty * 4 + i) * 256 + tc * 64 + tx * 4] = v;
    }
}

// ---------------- kernel 4: AT/BT = M2 @ diag(cos|sin(phases)) @ M1 -> bf16 -
__global__ __launch_bounds__(256) void k_abt(const float* __restrict__ mats,
                                             const float* __restrict__ phases,
                                             unsigned short* __restrict__ abt) {
    const float* Am = mats + 65536;    // M2
    const float* Bm = mats;            // M1
    const int v = blockIdx.y;          // 0: cos (AT), 1: sin (BT)
    const int tr = blockIdx.x >> 2, tc = blockIdx.x & 3;

    __shared__ float As[64 * 32];
    __shared__ float Bs[32 * 64];
    const int tid = threadIdx.x;
    const int tx = tid & 15, ty = tid >> 4;

    float acc[4][4] = {};
    for (int kb = 0; kb < 8; kb++) {
        __syncthreads();
        #pragma unroll
        for (int it = 0; it < 2; it++) {
            int flat = tid + it * 256;
            int r = flat >> 3, c4 = flat & 7;
            f32x4 vv = *(const f32x4*)&Am[(size_t)(tr * 64 + r) * 256 + kb * 32 + c4 * 4];
            *(f32x4*)&As[r * 32 + c4 * 4] = vv;
        }
        #pragma unroll
        for (int it = 0; it < 2; it++) {
            int flat = tid + it * 256;
            int r = flat >> 4, c4 = flat & 15;
            int kg = kb * 32 + r;
            float ph = phases[kg];
            float sc = v ? sinf(ph) : cosf(ph);
            f32x4 vv = *(const f32x4*)&Bm[(size_t)kg * 256 + tc * 64 + c4 * 4];
            vv[0] *= sc; vv[1] *= sc; vv[2] *= sc; vv[3] *= sc;
            *(f32x4*)&Bs[r * 64 + c4 * 4] = vv;
        }
        __syncthreads();
        #pragma unroll 8
        for (int kk = 0; kk < 32; kk++) {
            f32x4 bv = *(const f32x4*)&Bs[kk * 64 + tx * 4];
            float a0 = As[(ty * 4 + 0) * 32 + kk];
            float a1 = As[(ty * 4 + 1) * 32 + kk];
            float a2 = As[(ty * 4 + 2) * 32 + kk];
            float a3 = As[(ty * 4 + 3) * 32 + kk];
            #pragma unroll
            for (int j = 0; j < 4; j++) {
                acc[0][j] += a0 * bv[j];
                acc[1][j] += a1 * bv[j];
                acc[2][j] += a2 * bv[j];
                acc[3][j] += a3 * bv[j];
            }
        }
    }
    #pragma unroll
    for (int i = 0; i < 4; i++) {
        unsigned short h0 = f2bf(acc[i][0]), h1 = f2bf(acc[i][1]);
        unsigned short h2 = f2bf(acc[i][2]), h3 = f2bf(acc[i][3]);
        u32x2 pk = { (unsigned)h0 | ((unsigned)h1 << 16),
                     (unsigned)h2 | ((unsigned)h3 << 16) };
        *(u32x2*)&abt[(size_t)(v * 256 + tr * 64 + ty * 4 + i) * 256 + tc * 64 + tx * 4] = pk;
    }
}

// ---------------- kernel 5a: normalize rows -> bf16 (fast path) -------------
__global__ __launch_bounds__(256) void k_xnorm(const float* __restrict__ x,
                                               unsigned short* __restrict__ xbf) {
    const int row = blockIdx.x * 4 + (threadIdx.x >> 6);
    const int lane = threadIdx.x & 63;
    f32x4 v = *(const f32x4*)&x[(size_t)row * 256 + lane * 4];
    float s = v[0] * v[0] + v[1] * v[1] + v[2] * v[2] + v[3] * v[3];
    for (int off = 32; off; off >>= 1) s += __shfl_xor(s, off, 64);
    float sc = 1.0f / sqrtf(s);
    unsigned short h0 = f2bf(v[0] * sc), h1 = f2bf(v[1] * sc);
    unsigned short h2 = f2bf(v[2] * sc), h3 = f2bf(v[3] * sc);
    u32x2 pk = { (unsigned)h0 | ((unsigned)h1 << 16),
                 (unsigned)h2 | ((unsigned)h3 << 16) };
    *(u32x2*)&xbf[(size_t)row * 256 + lane * 4] = pk;
}

// ---------------- kernel 5b: per-row 1/||x|| (fallback path) ----------------
__global__ __launch_bounds__(256) void k_norm(const float* __restrict__ x,
                                              float* __restrict__ invn) {
    const int row = blockIdx.x * 4 + (threadIdx.x >> 6);
    const int lane = threadIdx.x & 63;
    f32x4 v = *(const f32x4*)&x[(size_t)row * 256 + lane * 4];
    float s = v[0] * v[0] + v[1] * v[1] + v[2] * v[2] + v[3] * v[3];
    for (int off = 32; off; off >>= 1) s += __shfl_xor(s, off, 64);
    if (lane == 0) invn[row] = 1.0f / sqrtf(s);
}

// ---------------- kernel 6a: GEMM + |.|^2 from pre-converted bf16 x ---------
// Grid (rb=512, cb=4): the 4 cb-blocks sharing an x-tile are 512 apart in
// linear WG id -> same XCD under round-robin dispatch -> x fetched once/XCD.
#define BKP 136   // padded LDS k-stride (bf16 elems)
__global__ __launch_bounds__(256) void k_gemm_bf(const unsigned short* __restrict__ xbf,
                                                 const unsigned short* __restrict__ abt,
                                                 float* __restrict__ out) {
    __shared__ unsigned short As[128 * BKP];
    __shared__ unsigned short Bs[128 * BKP];
    const int tid = threadIdx.x;
    const int rb = blockIdx.x;          // 0..511
    const int cb = blockIdx.y;          // 0..3  (64 out-cols each)
    const int lane = tid & 63, w = tid >> 6;

    f32x4 acc[16];
    #pragma unroll
    for (int i = 0; i < 16; i++) acc[i] = (f32x4){0.f, 0.f, 0.f, 0.f};

    for (int kb = 0; kb < 2; kb++) {
        __syncthreads();
        #pragma unroll
        for (int it = 0; it < 8; it++) {
            int flat = tid + it * 256;            // 128 rows x 16 chunks(8 bf16)
            int r = flat >> 4, c8 = flat & 15;
            u32x4 vv = *(const u32x4*)&xbf[(size_t)(rb * 128 + r) * 256 + kb * 128 + c8 * 8];
            *(u32x4*)&As[r * BKP + c8 * 8] = vv;
        }
        #pragma unroll
        for (int it = 0; it < 8; it++) {
            int flat = tid + it * 256;
            int r = flat >> 4, c8 = flat & 15;
            int gr = (r < 64) ? (cb * 64 + r) : (256 + cb * 64 + (r - 64));
            u32x4 vv = *(const u32x4*)&abt[(size_t)gr * 256 + kb * 128 + c8 * 8];
            *(u32x4*)&Bs[r * BKP + c8 * 8] = vv;
        }
        __syncthreads();
        #pragma unroll
        for (int ks = 0; ks < 4; ks++) {
            const int k0 = ks * 32 + (lane >> 4) * 8;
            s16x8 a[2], b[8];
            #pragma unroll
            for (int tm = 0; tm < 2; tm++)
                a[tm] = *(const s16x8*)&As[(w * 32 + tm * 16 + (lane & 15)) * BKP + k0];
            #pragma unroll
            for (int tn = 0; tn < 8; tn++)
                b[tn] = *(const s16x8*)&Bs[(tn * 16 + (lane & 15)) * BKP + k0];
            #pragma unroll
            for (int tm = 0; tm < 2; tm++)
                #pragma unroll
                for (int tn = 0; tn < 8; tn++)
                    acc[tm * 8 + tn] = __builtin_amdgcn_mfma_f32_16x16x32_bf16(
                        a[tm], b[tn], acc[tm * 8 + tn], 0, 0, 0);
        }
    }

    // epilogue: C/D layout col = lane&15, row = (lane>>4)*4 + reg
    const int qr = lane >> 4, c = lane & 15;
    #pragma unroll
    for (int tm = 0; tm < 2; tm++) {
        #pragma unroll
        for (int tn = 0; tn < 4; tn++) {
            f32x4 p = acc[tm * 8 + tn];
            f32x4 q = acc[tm * 8 + tn + 4];
            #pragma unroll
            for (int r = 0; r < 4; r++) {
                int m = w * 32 + tm * 16 + qr * 4 + r;
                out[(size_t)(rb * 128 + m) * 256 + cb * 64 + tn * 16 + c] =
                    p[r] * p[r] + q[r] * q[r];
            }
        }
    }
}

// ---------------- kernel 6b: GEMM + |.|^2 from fp32 x (fallback) ------------
__global__ __launch_bounds__(256) void k_gemm_f32(const float* __restrict__ x,
                                                  const unsigned short* __restrict__ abt,
                                                  const float* __restrict__ invn,
                                                  float* __restrict__ out) {
    __shared__ unsigned short As[128 * BKP];
    __shared__ unsigned short Bs[128 * BKP];
    const int tid = threadIdx.x;
    const int rb = blockIdx.x;
    const int cb = blockIdx.y;
    const int lane = tid & 63, w = tid >> 6;

    f32x4 acc[16];
    #pragma unroll
    for (int i = 0; i < 16; i++) acc[i] = (f32x4){0.f, 0.f, 0.f, 0.f};

    for (int kb = 0; kb < 2; kb++) {
        __syncthreads();
        #pragma unroll
        for (int it = 0; it < 16; it++) {
            int flat = tid + it * 256;
            int r = flat >> 5, c4 = flat & 31;
            f32x4 v = *(const f32x4*)&x[(size_t)(rb * 128 + r) * 256 + kb * 128 + c4 * 4];
            float sc = invn[rb * 128 + r];
            v[0] *= sc; v[1] *= sc; v[2] *= sc; v[3] *= sc;
            unsigned short h0 = f2bf(v[0]), h1 = f2bf(v[1]);
            unsigned short h2 = f2bf(v[2]), h3 = f2bf(v[3]);
            u32x2 pk = { (unsigned)h0 | ((unsigned)h1 << 16),
                         (unsigned)h2 | ((unsigned)h3 << 16) };
            *(u32x2*)&As[r * BKP + c4 * 4] = pk;
        }
        #pragma unroll
        for (int it = 0; it < 8; it++) {
            int flat = tid + it * 256;
            int r = flat >> 4, c8 = flat & 15;
            int gr = (r < 64) ? (cb * 64 + r) : (256 + cb * 64 + (r - 64));
            u32x4 vv = *(const u32x4*)&abt[(size_t)gr * 256 + kb * 128 + c8 * 8];
            *(u32x4*)&Bs[r * BKP + c8 * 8] = vv;
        }
        __syncthreads();
        #pragma unroll
        for (int ks = 0; ks < 4; ks++) {
            const int k0 = ks * 32 + (lane >> 4) * 8;
            s16x8 a[2], b[8];
            #pragma unroll
            for (int tm = 0; tm < 2; tm++)
                a[tm] = *(const s16x8*)&As[(w * 32 + tm * 16 + (lane & 15)) * BKP + k0];
            #pragma unroll
            for (int tn = 0; tn < 8; tn++)
                b[tn] = *(const s16x8*)&Bs[(tn * 16 + (lane & 15)) * BKP + k0];
            #pragma unroll
            for (int tm = 0; tm < 2; tm++)
                #pragma unroll
                for (int tn = 0; tn < 8; tn++)
                    acc[tm * 8 + tn] = __builtin_amdgcn_mfma_f32_16x16x32_bf16(
                        a[tm], b[tn], acc[tm * 8 + tn], 0, 0, 0);
        }
    }

    const int qr = lane >> 4, c = lane & 15;
    #pragma unroll
    for (int tm = 0; tm < 2; tm++) {
        #pragma unroll
        for (int tn = 0; tn < 4; tn++) {
            f32x4 p = acc[tm * 8 + tn];
            f32x4 q = acc[tm * 8 + tn + 4];
            #pragma unroll
            for (int r = 0; r < 4; r++) {
                int m = w * 32 + tm * 16 + qr * 4 + r;
                out[(size_t)(rb * 128 + m) * 256 + cb * 64 + tn * 16 + c] =
                    p[r] * p[r] + q[r] * q[r];
            }
        }
    }
}

// ---------------- host ------------------------------------------------------
extern "C" void kernel_launch(void* const* d_in, const int* in_sizes, int n_in,
                              void* d_out, int out_size, void* d_ws, size_t ws_size,
                              hipStream_t stream) {
    (void)in_sizes; (void)n_in; (void)out_size;
    const float* x      = (const float*)d_in[0];
    const float* rots1  = (const float*)d_in[1];
    const float* phases = (const float*)d_in[2];
    const float* rots2  = (const float*)d_in[3];
    float* out = (float*)d_out;
    char* ws = (char*)d_ws;

    // ws-adaptive parallel-block count (deterministic: ws_size fixed per run)
    const size_t MAT = 262144;                 // 256x256 fp32
    int pblk = 64;
    while (pblk > 16 &&
           524288 + (size_t)3 * pblk * MAT + 2 * MAT + (size_t)BATCH * 512 > ws_size)
        pblk >>= 1;
    const size_t offA   = 524288;
    const size_t offB   = offA + (size_t)2 * pblk * MAT;   // A: 2*pblk mats
    const size_t offABT = offB + (size_t)pblk * MAT;       // B: pblk mats
    const size_t offINV = offABT + MAT;
    const size_t offXBF = offINV + MAT;
    const bool use_xbf = (offXBF + (size_t)BATCH * 512) <= ws_size;

    float2*         cs   = (float2*)(ws);
    float*          A    = (float*)(ws + offA);
    float*          B    = (float*)(ws + offB);
    unsigned short* abt  = (unsigned short*)(ws + offABT);
    float*          invn = (float*)(ws + offINV);
    unsigned short* xbf  = (unsigned short*)(ws + offXBF);

    k_cossin<<<(2 * NROT + 255) / 256, 256, 0, stream>>>(rots1, rots2, cs);
    k_blocks<<<dim3(4, pblk, 2), 64, 0, stream>>>(cs, A, pblk);

    float* srcp = A; float* dstp = B;
    for (int half = pblk / 2; half >= 1; half >>= 1) {
        k_combine<<<dim3(16, 2 * half), 256, 0, stream>>>(srcp, dstp, half);
        float* tmp = srcp; srcp = dstp; dstp = tmp;
    }
    k_abt<<<dim3(16, 2), 256, 0, stream>>>(srcp, phases, abt);

    if (use_xbf) {
        k_xnorm<<<BATCH / 4, 256, 0, stream>>>(x, xbf);
        k_gemm_bf<<<dim3(BATCH / 128, 4), 256, 0, stream>>>(xbf, abt, out);
    } else {
        k_norm<<<BATCH / 4, 256, 0, stream>>>(x, invn);
        k_gemm_f32<<<dim3(BATCH / 128, 4), 256, 0, stream>>>(x, abt, invn, out);
    }
}

// Round 7
// 322.979 us; speedup vs baseline: 1.2091x; 1.0537x over previous
//
#include <hip/hip_runtime.h>
#include <stdint.h>
#include <math.h>

#define NDIM 256
#define BATCH 65536
#define NROT 32640          // 256*255/2

typedef float  f32x4 __attribute__((ext_vector_type(4)));
typedef short  s16x8 __attribute__((ext_vector_type(8)));
typedef unsigned int u32x4 __attribute__((ext_vector_type(4)));
typedef unsigned int u32x2 __attribute__((ext_vector_type(2)));

// round-to-nearest-even float -> bf16 bits
static __device__ __forceinline__ unsigned short f2bf(float f) {
    unsigned int u = __float_as_uint(f);
    u += 0x7fffu + ((u >> 16) & 1u);
    return (unsigned short)(u >> 16);
}

// nearest 4-aligned sweep boundary to k*(NROT/pblk); shared by k_blocks
// and k_combine (the block-diagonal skip logic depends on agreement).
static __device__ __forceinline__ int sweep_bound(int k, int pblk) {
    int target = k * (NROT / pblk);
    int best = 0, bd = 0x7fffffff;
    for (int i = 0; i <= 256; i += 4) {
        int pre = i * 255 - (i * (i - 1)) / 2;
        int d = pre - target; d = (d < 0) ? -d : d;
        if (d < bd) { bd = d; best = i; }
    }
    return best;
}

// ---------------- kernel 1: build pblk partial Givens products per matrix ---
// 4 sweeps fused (skewed schedule, order-equivalent: disjoint-row rotations
// commute). Active rows u0..u3 in registers. Angles computed inline
// (sincosf) during LDS staging; hot loop touches ONLY LDS (R4 lesson: no
// SMEM/global in the loop). Identity padding makes the steady loop guard-free
// with a fixed unroll-8 body. Partial product is identity above sweep s0 ->
// block-diagonal structure exploited by k_combine.
__global__ __launch_bounds__(64) void k_blocks(const float* __restrict__ r1,
                                               const float* __restrict__ r2,
                                               float* __restrict__ bmats, int pblk) {
    __shared__ float colb[264 * 64];
    __shared__ float2 csb[256 * 4];     // one group's steady angles, [jj][a]
    __shared__ float2 tri[24 * 6];      // all groups' triangle angles
    const int t = threadIdx.x;          // column within chunk
    const int chunk = blockIdx.x;       // 0..3 (64 cols each)
    const int b = blockIdx.y;           // 0..pblk-1
    const int set = blockIdx.z;         // 0 = rots1, 1 = rots2
    const int col0 = chunk * 64;
    const float* rots = set ? r2 : r1;

    const int s0 = sweep_bound(b, pblk);
    const int s1 = sweep_bound(b + 1, pblk);
    const int ngroups = (s1 - s0) >> 2;

    // zero colb (incl. pad rows 256..263), set identity diagonal
    {
        const f32x4 z = {0.f, 0.f, 0.f, 0.f};
        #pragma unroll 11
        for (int q = 0; q < 66; q++)
            *(f32x4*)&colb[(q * 64 + t) * 4] = z;
        colb[(col0 + t) * 64 + t] = 1.0f;
    }

    // stage all triangle angles (6 per group) into LDS
    // q -> pair (a,bb): 0->(0,1) 1->(0,2) 2->(0,3) 3->(1,2) 4->(1,3) 5->(2,3)
    for (int k = t; k < ngroups * 6; k += 64) {
        int g = k / 6, q = k - g * 6;
        int a  = (q < 3) ? 0 : ((q < 5) ? 1 : 2);
        int bb = (q < 3) ? (q + 1) : ((q < 5) ? (q - 1) : 3);
        int m0 = s0 + g * 4;
        int m = m0 + a;
        int base = m * 255 - (m * (m - 1)) / 2;
        float th = rots[base - m - 1 + (m0 + bb)];
        float sv, cv; sincosf(th, &sv, &cv);
        tri[k] = make_float2(cv, sv);
    }
    // single-wave WG: DS pipe is in-order per wave, no barrier needed

    for (int g = 0; g < ngroups; g++) {
        const int m0 = s0 + g * 4;
        int off[4];
        #pragma unroll
        for (int a = 0; a < 4; a++) {
            int m = m0 + a;
            int base = m * 255 - (m * (m - 1)) / 2;
            off[a] = base - m - 1;                  // angle for (m,j) = rots[off[a]+j]
        }
        const int n_j = 252 - m0;                   // #j in [m0+4, 256)
        const int n_p = (n_j > 0) ? ((n_j + 7) & ~7) : 0;

        // stage steady angles with identity padding: csb[jj*4 + a]
        for (int k = t; k < n_p * 4; k += 64) {
            int jj = k >> 2, a = k & 3;
            int j = m0 + 4 + jj;
            if (j < 256) {
                float th = rots[off[a] + j];
                float sv, cv; sincosf(th, &sv, &cv);
                csb[k] = make_float2(cv, sv);
            } else {
                csb[k] = make_float2(1.f, 0.f);
            }
        }

        // active rows -> registers
        float u0 = colb[(m0 + 0) * 64 + t];
        float u1 = colb[(m0 + 1) * 64 + t];
        float u2 = colb[(m0 + 2) * 64 + t];
        float u3 = colb[(m0 + 3) * 64 + t];

        // triangle peel: (m0,m0+1..3), (m0+1,m0+2..3), (m0+2,m0+3)
        {
            float2 cv; float nr;
            cv = tri[g * 6 + 0]; nr = cv.y * u0 + cv.x * u1; u0 = cv.x * u0 - cv.y * u1; u1 = nr;
            cv = tri[g * 6 + 1]; nr = cv.y * u0 + cv.x * u2; u0 = cv.x * u0 - cv.y * u2; u2 = nr;
            cv = tri[g * 6 + 2]; nr = cv.y * u0 + cv.x * u3; u0 = cv.x * u0 - cv.y * u3; u3 = nr;
            cv = tri[g * 6 + 3]; nr = cv.y * u1 + cv.x * u2; u1 = cv.x * u1 - cv.y * u2; u2 = nr;
            cv = tri[g * 6 + 4]; nr = cv.y * u1 + cv.x * u3; u1 = cv.x * u1 - cv.y * u3; u3 = nr;
            cv = tri[g * 6 + 5]; nr = cv.y * u2 + cv.x * u3; u2 = cv.x * u2 - cv.y * u3; u3 = nr;
        }

        // steady state: guard-free, unroll 8, 8-deep row prefetch
        if (n_p > 0) {
            float rbuf[8];
            #pragma unroll
            for (int p = 0; p < 8; p++)
                rbuf[p] = colb[(m0 + 4 + p) * 64 + t];
            for (int c = 0; c < n_p; c += 8) {
                #pragma unroll
                for (int p = 0; p < 8; p++) {
                    const int j = m0 + 4 + c + p;
                    float r = rbuf[p];
                    int jn = j + 8; jn = (jn < 263) ? jn : 263;
                    rbuf[p] = colb[jn * 64 + t];
                    float2 a0 = csb[(c + p) * 4 + 0];
                    float2 a1 = csb[(c + p) * 4 + 1];
                    float2 a2 = csb[(c + p) * 4 + 2];
                    float2 a3 = csb[(c + p) * 4 + 3];
                    float nr;
                    nr = a0.y * u0 + a0.x * r; u0 = a0.x * u0 - a0.y * r; r = nr;
                    nr = a1.y * u1 + a1.x * r; u1 = a1.x * u1 - a1.y * r; r = nr;
                    nr = a2.y * u2 + a2.x * r; u2 = a2.x * u2 - a2.y * r; r = nr;
                    nr = a3.y * u3 + a3.x * r; u3 = a3.x * u3 - a3.y * r; r = nr;
                    colb[j * 64 + t] = r;
                }
            }
        }
        colb[(m0 + 0) * 64 + t] = u0;
        colb[(m0 + 1) * 64 + t] = u1;
        colb[(m0 + 2) * 64 + t] = u2;
        colb[(m0 + 3) * 64 + t] = u3;
    }

    float* outm = bmats + (size_t)(set * pblk + b) * 65536;
    for (int r = 0; r < 256; r++)
        outm[(size_t)r * 256 + col0 + t] = colb[r * 64 + t];
}

// ---------------- kernel 2: pairwise combine round (fp32 256^3 matmul) ------
// dst[p] = src[2p+1] @ src[2p]. A = src[2p+1] is identity above sweep s0A
// (block-diagonal) -> tiles with all rows < s0A are a copy of B; tiles with
// all rows >= s0A skip k-blocks below s0A. As padded to stride 36 to break
// the stride-32 4-way bank conflict on the column reads.
__global__ __launch_bounds__(256) void k_combine(const float* __restrict__ src,
                                                 float* __restrict__ dst,
                                                 int half, int pblk) {
    const int by = blockIdx.y;
    const int set = by / half, pidx = by % half;
    const int stride = pblk / (2 * half);
    const int s0A = sweep_bound((2 * pidx + 1) * stride, pblk);
    const float* Am = src + (size_t)(set * 2 * half + 2 * pidx + 1) * 65536;
    const float* Bm = src + (size_t)(set * 2 * half + 2 * pidx) * 65536;
    float* Dm = dst + (size_t)(set * half + pidx) * 65536;
    const int tr = blockIdx.x >> 2, tc = blockIdx.x & 3;
    const int tid = threadIdx.x;

    if (tr * 64 + 64 <= s0A) {                 // pure copy tile: D = B
        #pragma unroll
        for (int it = 0; it < 4; it++) {
            int flat = tid + it * 256;         // 64 rows x 16 float4
            int r = flat >> 4, c4 = flat & 15;
            size_t idx = (size_t)(tr * 64 + r) * 256 + tc * 64 + c4 * 4;
            *(f32x4*)&Dm[idx] = *(const f32x4*)&Bm[idx];
        }
        return;
    }
    const int kb0 = (tr * 64 >= s0A) ? (s0A >> 5) : 0;

    __shared__ float As[64 * 36];              // padded: stride 36
    __shared__ float Bs[32 * 64];
    const int tx = tid & 15, ty = tid >> 4;

    float acc[4][4] = {};
    for (int kb = kb0; kb < 8; kb++) {
        __syncthreads();
        #pragma unroll
        for (int it = 0; it < 2; it++) {       // A: 64x32 = 512 float4
            int flat = tid + it * 256;
            int r = flat >> 3, c4 = flat & 7;
            f32x4 v = *(const f32x4*)&Am[(size_t)(tr * 64 + r) * 256 + kb * 32 + c4 * 4];
            *(f32x4*)&As[r * 36 + c4 * 4] = v;
        }
        #pragma unroll
        for (int it = 0; it < 2; it++) {       // B: 32x64 = 512 float4
            int flat = tid + it * 256;
            int r = flat >> 4, c4 = flat & 15;
            f32x4 v = *(const f32x4*)&Bm[(size_t)(kb * 32 + r) * 256 + tc * 64 + c4 * 4];
            *(f32x4*)&Bs[r * 64 + c4 * 4] = v;
        }
        __syncthreads();
        #pragma unroll 8
        for (int kk = 0; kk < 32; kk++) {
            f32x4 bv = *(const f32x4*)&Bs[kk * 64 + tx * 4];
            float a0 = As[(ty * 4 + 0) * 36 + kk];
            float a1 = As[(ty * 4 + 1) * 36 + kk];
            float a2 = As[(ty * 4 + 2) * 36 + kk];
            float a3 = As[(ty * 4 + 3) * 36 + kk];
            #pragma unroll
            for (int j = 0; j < 4; j++) {
                acc[0][j] += a0 * bv[j];
                acc[1][j] += a1 * bv[j];
                acc[2][j] += a2 * bv[j];
                acc[3][j] += a3 * bv[j];
            }
        }
    }
    #pragma unroll
    for (int i = 0; i < 4; i++) {
        f32x4 v = { acc[i][0], acc[i][1], acc[i][2], acc[i][3] };
        *(f32x4*)&Dm[(size_t)(tr * 64 + ty * 4 + i) * 256 + tc * 64 + tx * 4] = v;
    }
}

// ---------------- kernel 3: AT/BT = M2 @ diag(cos|sin(phases)) @ M1 -> bf16 -
__global__ __launch_bounds__(256) void k_abt(const float* __restrict__ mats,
                                             const float* __restrict__ phases,
                                             unsigned short* __restrict__ abt) {
    const float* Am = mats + 65536;    // M2
    const float* Bm = mats;            // M1
    const int v = blockIdx.y;          // 0: cos (AT), 1: sin (BT)
    const int tr = blockIdx.x >> 2, tc = blockIdx.x & 3;

    __shared__ float As[64 * 36];
    __shared__ float Bs[32 * 64];
    const int tid = threadIdx.x;
    const int tx = tid & 15, ty = tid >> 4;

    float acc[4][4] = {};
    for (int kb = 0; kb < 8; kb++) {
        __syncthreads();
        #pragma unroll
        for (int it = 0; it < 2; it++) {
            int flat = tid + it * 256;
            int r = flat >> 3, c4 = flat & 7;
            f32x4 vv = *(const f32x4*)&Am[(size_t)(tr * 64 + r) * 256 + kb * 32 + c4 * 4];
            *(f32x4*)&As[r * 36 + c4 * 4] = vv;
        }
        #pragma unroll
        for (int it = 0; it < 2; it++) {
            int flat = tid + it * 256;
            int r = flat >> 4, c4 = flat & 15;
            int kg = kb * 32 + r;
            float ph = phases[kg];
            float sc = v ? sinf(ph) : cosf(ph);
            f32x4 vv = *(const f32x4*)&Bm[(size_t)kg * 256 + tc * 64 + c4 * 4];
            vv[0] *= sc; vv[1] *= sc; vv[2] *= sc; vv[3] *= sc;
            *(f32x4*)&Bs[r * 64 + c4 * 4] = vv;
        }
        __syncthreads();
        #pragma unroll 8
        for (int kk = 0; kk < 32; kk++) {
            f32x4 bv = *(const f32x4*)&Bs[kk * 64 + tx * 4];
            float a0 = As[(ty * 4 + 0) * 36 + kk];
            float a1 = As[(ty * 4 + 1) * 36 + kk];
            float a2 = As[(ty * 4 + 2) * 36 + kk];
            float a3 = As[(ty * 4 + 3) * 36 + kk];
            #pragma unroll
            for (int j = 0; j < 4; j++) {
                acc[0][j] += a0 * bv[j];
                acc[1][j] += a1 * bv[j];
                acc[2][j] += a2 * bv[j];
                acc[3][j] += a3 * bv[j];
            }
        }
    }
    #pragma unroll
    for (int i = 0; i < 4; i++) {
        unsigned short h0 = f2bf(acc[i][0]), h1 = f2bf(acc[i][1]);
        unsigned short h2 = f2bf(acc[i][2]), h3 = f2bf(acc[i][3]);
        u32x2 pk = { (unsigned)h0 | ((unsigned)h1 << 16),
                     (unsigned)h2 | ((unsigned)h3 << 16) };
        *(u32x2*)&abt[(size_t)(v * 256 + tr * 64 + ty * 4 + i) * 256 + tc * 64 + tx * 4] = pk;
    }
}

// ---------------- kernel 4a: normalize rows -> bf16 (fast path) -------------
__global__ __launch_bounds__(256) void k_xnorm(const float* __restrict__ x,
                                               unsigned short* __restrict__ xbf) {
    const int row = blockIdx.x * 4 + (threadIdx.x >> 6);
    const int lane = threadIdx.x & 63;
    f32x4 v = *(const f32x4*)&x[(size_t)row * 256 + lane * 4];
    float s = v[0] * v[0] + v[1] * v[1] + v[2] * v[2] + v[3] * v[3];
    for (int off = 32; off; off >>= 1) s += __shfl_xor(s, off, 64);
    float sc = 1.0f / sqrtf(s);
    unsigned short h0 = f2bf(v[0] * sc), h1 = f2bf(v[1] * sc);
    unsigned short h2 = f2bf(v[2] * sc), h3 = f2bf(v[3] * sc);
    u32x2 pk = { (unsigned)h0 | ((unsigned)h1 << 16),
                 (unsigned)h2 | ((unsigned)h3 << 16) };
    *(u32x2*)&xbf[(size_t)row * 256 + lane * 4] = pk;
}

// ---------------- kernel 4b: per-row 1/||x|| (fallback path) ----------------
__global__ __launch_bounds__(256) void k_norm(const float* __restrict__ x,
                                              float* __restrict__ invn) {
    const int row = blockIdx.x * 4 + (threadIdx.x >> 6);
    const int lane = threadIdx.x & 63;
    f32x4 v = *(const f32x4*)&x[(size_t)row * 256 + lane * 4];
    float s = v[0] * v[0] + v[1] * v[1] + v[2] * v[2] + v[3] * v[3];
    for (int off = 32; off; off >>= 1) s += __shfl_xor(s, off, 64);
    if (lane == 0) invn[row] = 1.0f / sqrtf(s);
}

// ---------------- kernel 5a: GEMM + |.|^2 from pre-converted bf16 x ---------
// Grid (cb=4, rb=512), cb minor: the 4 cb WGs sharing an x-tile dispatch
// back-to-back -> concurrent -> x served from L2/L3 after first touch.
// kb=1 tiles are prefetched into registers while kb=0 MFMAs run.
#define BKP 136   // padded LDS k-stride (bf16 elems)
__global__ __launch_bounds__(256) void k_gemm_bf(const unsigned short* __restrict__ xbf,
                                                 const unsigned short* __restrict__ abt,
                                                 float* __restrict__ out) {
    __shared__ unsigned short As[128 * BKP];
    __shared__ unsigned short Bs[128 * BKP];
    const int tid = threadIdx.x;
    const int cb = blockIdx.x;          // 0..3  (64 out-cols each)
    const int rb = blockIdx.y;          // 0..511
    const int lane = tid & 63, w = tid >> 6;

    f32x4 acc[16];
    #pragma unroll
    for (int i = 0; i < 16; i++) acc[i] = (f32x4){0.f, 0.f, 0.f, 0.f};

    int rA[8], cA[8], grB[8];
    #pragma unroll
    for (int it = 0; it < 8; it++) {
        int flat = tid + it * 256;
        rA[it] = flat >> 4; cA[it] = flat & 15;
        int r = rA[it];
        grB[it] = (r < 64) ? (cb * 64 + r) : (256 + cb * 64 + (r - 64));
    }

    u32x4 pa[8], pb[8];
    // load kb=0 tiles
    #pragma unroll
    for (int it = 0; it < 8; it++) {
        pa[it] = *(const u32x4*)&xbf[(size_t)(rb * 128 + rA[it]) * 256 + cA[it] * 8];
        pb[it] = *(const u32x4*)&abt[(size_t)grB[it] * 256 + cA[it] * 8];
    }
    #pragma unroll
    for (int it = 0; it < 8; it++) {
        *(u32x4*)&As[rA[it] * BKP + cA[it] * 8] = pa[it];
        *(u32x4*)&Bs[rA[it] * BKP + cA[it] * 8] = pb[it];
    }
    __syncthreads();
    // issue kb=1 loads (in flight during kb=0 compute)
    #pragma unroll
    for (int it = 0; it < 8; it++) {
        pa[it] = *(const u32x4*)&xbf[(size_t)(rb * 128 + rA[it]) * 256 + 128 + cA[it] * 8];
        pb[it] = *(const u32x4*)&abt[(size_t)grB[it] * 256 + 128 + cA[it] * 8];
    }

    auto compute = [&]() {
        #pragma unroll
        for (int ks = 0; ks < 4; ks++) {
            const int k0 = ks * 32 + (lane >> 4) * 8;
            s16x8 a[2], b[8];
            #pragma unroll
            for (int tm = 0; tm < 2; tm++)
                a[tm] = *(const s16x8*)&As[(w * 32 + tm * 16 + (lane & 15)) * BKP + k0];
            #pragma unroll
            for (int tn = 0; tn < 8; tn++)
                b[tn] = *(const s16x8*)&Bs[(tn * 16 + (lane & 15)) * BKP + k0];
            #pragma unroll
            for (int tm = 0; tm < 2; tm++)
                #pragma unroll
                for (int tn = 0; tn < 8; tn++)
                    acc[tm * 8 + tn] = __builtin_amdgcn_mfma_f32_16x16x32_bf16(
                        a[tm], b[tn], acc[tm * 8 + tn], 0, 0, 0);
        }
    };
    compute();                 // kb=0
    __syncthreads();
    #pragma unroll
    for (int it = 0; it < 8; it++) {
        *(u32x4*)&As[rA[it] * BKP + cA[it] * 8] = pa[it];
        *(u32x4*)&Bs[rA[it] * BKP + cA[it] * 8] = pb[it];
    }
    __syncthreads();
    compute();                 // kb=1

    // epilogue: C/D layout col = lane&15, row = (lane>>4)*4 + reg
    const int qr = lane >> 4, c = lane & 15;
    #pragma unroll
    for (int tm = 0; tm < 2; tm++) {
        #pragma unroll
        for (int tn = 0; tn < 4; tn++) {
            f32x4 p = acc[tm * 8 + tn];
            f32x4 q = acc[tm * 8 + tn + 4];
            #pragma unroll
            for (int r = 0; r < 4; r++) {
                int m = w * 32 + tm * 16 + qr * 4 + r;
                out[(size_t)(rb * 128 + m) * 256 + cb * 64 + tn * 16 + c] =
                    p[r] * p[r] + q[r] * q[r];
            }
        }
    }
}

// ---------------- kernel 5b: GEMM + |.|^2 from fp32 x (fallback) ------------
__global__ __launch_bounds__(256) void k_gemm_f32(const float* __restrict__ x,
                                                  const unsigned short* __restrict__ abt,
                                                  const float* __restrict__ invn,
                                                  float* __restrict__ out) {
    __shared__ unsigned short As[128 * BKP];
    __shared__ unsigned short Bs[128 * BKP];
    const int tid = threadIdx.x;
    const int cb = blockIdx.x;
    const int rb = blockIdx.y;
    const int lane = tid & 63, w = tid >> 6;

    f32x4 acc[16];
    #pragma unroll
    for (int i = 0; i < 16; i++) acc[i] = (f32x4){0.f, 0.f, 0.f, 0.f};

    for (int kb = 0; kb < 2; kb++) {
        __syncthreads();
        #pragma unroll
        for (int it = 0; it < 16; it++) {
            int flat = tid + it * 256;
            int r = flat >> 5, c4 = flat & 31;
            f32x4 v = *(const f32x4*)&x[(size_t)(rb * 128 + r) * 256 + kb * 128 + c4 * 4];
            float sc = invn[rb * 128 + r];
            v[0] *= sc; v[1] *= sc; v[2] *= sc; v[3] *= sc;
            unsigned short h0 = f2bf(v[0]), h1 = f2bf(v[1]);
            unsigned short h2 = f2bf(v[2]), h3 = f2bf(v[3]);
            u32x2 pk = { (unsigned)h0 | ((unsigned)h1 << 16),
                         (unsigned)h2 | ((unsigned)h3 << 16) };
            *(u32x2*)&As[r * BKP + c4 * 4] = pk;
        }
        #pragma unroll
        for (int it = 0; it < 8; it++) {
            int flat = tid + it * 256;
            int r = flat >> 4, c8 = flat & 15;
            int gr = (r < 64) ? (cb * 64 + r) : (256 + cb * 64 + (r - 64));
            u32x4 vv = *(const u32x4*)&abt[(size_t)gr * 256 + kb * 128 + c8 * 8];
            *(u32x4*)&Bs[r * BKP + c8 * 8] = vv;
        }
        __syncthreads();
        #pragma unroll
        for (int ks = 0; ks < 4; ks++) {
            const int k0 = ks * 32 + (lane >> 4) * 8;
            s16x8 a[2], b[8];
            #pragma unroll
            for (int tm = 0; tm < 2; tm++)
                a[tm] = *(const s16x8*)&As[(w * 32 + tm * 16 + (lane & 15)) * BKP + k0];
            #pragma unroll
            for (int tn = 0; tn < 8; tn++)
                b[tn] = *(const s16x8*)&Bs[(tn * 16 + (lane & 15)) * BKP + k0];
            #pragma unroll
            for (int tm = 0; tm < 2; tm++)
                #pragma unroll
                for (int tn = 0; tn < 8; tn++)
                    acc[tm * 8 + tn] = __builtin_amdgcn_mfma_f32_16x16x32_bf16(
                        a[tm], b[tn], acc[tm * 8 + tn], 0, 0, 0);
        }
    }

    const int qr = lane >> 4, c = lane & 15;
    #pragma unroll
    for (int tm = 0; tm < 2; tm++) {
        #pragma unroll
        for (int tn = 0; tn < 4; tn++) {
            f32x4 p = acc[tm * 8 + tn];
            f32x4 q = acc[tm * 8 + tn + 4];
            #pragma unroll
            for (int r = 0; r < 4; r++) {
                int m = w * 32 + tm * 16 + qr * 4 + r;
                out[(size_t)(rb * 128 + m) * 256 + cb * 64 + tn * 16 + c] =
                    p[r] * p[r] + q[r] * q[r];
            }
        }
    }
}

// ---------------- host ------------------------------------------------------
extern "C" void kernel_launch(void* const* d_in, const int* in_sizes, int n_in,
                              void* d_out, int out_size, void* d_ws, size_t ws_size,
                              hipStream_t stream) {
    (void)in_sizes; (void)n_in; (void)out_size;
    const float* x      = (const float*)d_in[0];
    const float* rots1  = (const float*)d_in[1];
    const float* phases = (const float*)d_in[2];
    const float* rots2  = (const float*)d_in[3];
    float* out = (float*)d_out;
    char* ws = (char*)d_ws;

    const size_t MAT = 262144;                 // 256x256 fp32
    int pblk = 32;
    while (pblk > 16 &&
           (size_t)3 * pblk * MAT + 2 * MAT + (size_t)BATCH * 512 > ws_size)
        pblk >>= 1;
    const size_t offA   = 0;
    const size_t offB   = offA + (size_t)2 * pblk * MAT;   // A: 2*pblk mats
    const size_t offABT = offB + (size_t)pblk * MAT;       // B: pblk mats
    const size_t offINV = offABT + MAT;
    const size_t offXBF = offINV + MAT;
    const bool use_xbf = (offXBF + (size_t)BATCH * 512) <= ws_size;

    float*          A    = (float*)(ws + offA);
    float*          B    = (float*)(ws + offB);
    unsigned short* abt  = (unsigned short*)(ws + offABT);
    float*          invn = (float*)(ws + offINV);
    unsigned short* xbf  = (unsigned short*)(ws + offXBF);

    k_blocks<<<dim3(4, pblk, 2), 64, 0, stream>>>(rots1, rots2, A, pblk);

    float* srcp = A; float* dstp = B;
    for (int half = pblk / 2; half >= 1; half >>= 1) {
        k_combine<<<dim3(16, 2 * half), 256, 0, stream>>>(srcp, dstp, half, pblk);
        float* tmp = srcp; srcp = dstp; dstp = tmp;
    }
    k_abt<<<dim3(16, 2), 256, 0, stream>>>(srcp, phases, abt);

    if (use_xbf) {
        k_xnorm<<<BATCH / 4, 256, 0, stream>>>(x, xbf);
        k_gemm_bf<<<dim3(4, BATCH / 128), 256, 0, stream>>>(xbf, abt, out);
    } else {
        k_norm<<<BATCH / 4, 256, 0, stream>>>(x, invn);
        k_gemm_f32<<<dim3(4, BATCH / 128), 256, 0, stream>>>(x, abt, invn, out);
    }
}